// Round 7
// baseline (31826.379 us; speedup 1.0000x reference)
//
#include <hip/hip_runtime.h>
#include <math.h>

// Problem dims
#define B_   128
#define S_   400
#define ENC_ 512
#define E_   256
#define H_   512
#define D_   128
#define P_   128
#define V_   30
#define T_   600

// Workspace layout (float units) — KV fp32
#define KEYV_OFF 0
#define VALV_OFF (KEYV_OFF + B_*S_*P_)
#define H1_OFF   (VALV_OFF + B_*S_*P_)
#define C1_OFF   (H1_OFF + 2*B_*H_)
#define H2_OFF   (C1_OFF + B_*H_)
#define C2_OFF   (H2_OFF + 2*B_*D_)
#define CTX_OFF  (C2_OFF + B_*D_)
#define CHR_OFF  (CTX_OFF + B_*P_)
#define PV1_OFF  (CHR_OFF + B_)          // [128][128] half-1 partial PV
#define MS1_OFF  (PV1_OFF + B_*P_)       // [128][2]  half-1 (m, sum)
#define ES1_OFF  (MS1_OFF + 2*B_)        // [204]     half-1 exp-scores of item 0 (plot)
#define WS_FLOATS (ES1_OFF + 204)        // barrier ints live at ws[WS_FLOATS..]

#define PRED_N (B_*T_*V_)
#define NBLK 256
#define NTHR 512

// LDS float offsets (k-major weight slices, persistent)
#define W1_BASE 0                        // [896][16]
#define W2_BASE 14336                    // [640][16]
#define SCR     24576                    // per-phase scratch (13120 floats)
#define LDS_FLOATS (SCR + 13120)         // 37696 floats = 150784 B

__device__ __forceinline__ float sigm_(float x){ return 1.0f/(1.0f + expf(-x)); }

// --- agent-scope relaxed atomics (sc1): bypass L1/L2, see coherence point ---
__device__ __forceinline__ float ldA(const float* p){
  return __hip_atomic_load(p, __ATOMIC_RELAXED, __HIP_MEMORY_SCOPE_AGENT);
}
__device__ __forceinline__ void stA(float* p, float v){
  __hip_atomic_store(p, v, __ATOMIC_RELAXED, __HIP_MEMORY_SCOPE_AGENT);
}
__device__ __forceinline__ int ldAi(const int* p){
  return __hip_atomic_load(p, __ATOMIC_RELAXED, __HIP_MEMORY_SCOPE_AGENT);
}
__device__ __forceinline__ void stAi(int* p, int v){
  __hip_atomic_store(p, v, __ATOMIC_RELAXED, __HIP_MEMORY_SCOPE_AGENT);
}

// ---- fence-free grid barrier (round-3/4/6 proven) ----
__device__ __forceinline__ void gbar(int* bar){
  __syncthreads();
  if (threadIdx.x == 0){
    const int g0 = __hip_atomic_load(bar, __ATOMIC_RELAXED, __HIP_MEMORY_SCOPE_AGENT);
    asm volatile("" ::: "memory");
    int* leaf = bar + 64 + (blockIdx.x & 7)*32;
    int lo = __hip_atomic_fetch_add(leaf, 1, __ATOMIC_RELAXED, __HIP_MEMORY_SCOPE_AGENT);
    bool done = false;
    if (lo == 31){
      int ro = __hip_atomic_fetch_add(bar+32, 1, __ATOMIC_RELAXED, __HIP_MEMORY_SCOPE_AGENT);
      if (ro == 7){
        #pragma unroll
        for (int i=0;i<8;++i)
          __hip_atomic_store(bar+64+i*32, 0, __ATOMIC_RELAXED, __HIP_MEMORY_SCOPE_AGENT);
        __hip_atomic_store(bar+32, 0, __ATOMIC_RELAXED, __HIP_MEMORY_SCOPE_AGENT);
        asm volatile("s_waitcnt vmcnt(0)" ::: "memory");
        __hip_atomic_fetch_add(bar, 1, __ATOMIC_RELAXED, __HIP_MEMORY_SCOPE_AGENT);
        done = true;
      }
    }
    if (!done){
      while (__hip_atomic_load(bar, __ATOMIC_RELAXED, __HIP_MEMORY_SCOPE_AGENT) == g0)
        __builtin_amdgcn_s_sleep(4);
    }
  }
  __syncthreads();
}

// ---------------- precompute keyv/valv fp32 (proven) ------------------------------------
__global__ __launch_bounds__(256) void k_kv(const float* __restrict__ enc,
    const float* __restrict__ Wk, const float* __restrict__ bk,
    const float* __restrict__ Wv, const float* __restrict__ bv,
    float* __restrict__ ws)
{
  __shared__ float As[32][68];
  __shared__ float Bs[32][68];
  const int tid = threadIdx.x;
  const int tx = tid & 15, ty = tid >> 4;
  const int n0 = blockIdx.x * 64;
  const int c0 = blockIdx.y * 64;
  float acc[4][4] = {};
  for (int k0 = 0; k0 < ENC_; k0 += 32){
    #pragma unroll
    for (int i = 0; i < 8; ++i){
      int idx = tid + 256*i;
      int kk = idx & 31, nl = idx >> 5;
      As[kk][nl] = enc[(size_t)(n0+nl)*ENC_ + k0 + kk];
    }
    #pragma unroll
    for (int i = 0; i < 8; ++i){
      int idx = tid + 256*i;
      int kk = idx & 31, cl = idx >> 5;
      int c = c0 + cl; int p = c & 127;
      const float* W = (c < 128) ? Wk : Wv;
      Bs[kk][cl] = W[(size_t)p*ENC_ + k0 + kk];
    }
    __syncthreads();
    #pragma unroll
    for (int kk = 0; kk < 32; ++kk){
      float4 a4 = *(const float4*)&As[kk][ty*4];
      float4 b4 = *(const float4*)&Bs[kk][tx*4];
      float aa[4] = {a4.x, a4.y, a4.z, a4.w};
      float bb[4] = {b4.x, b4.y, b4.z, b4.w};
      #pragma unroll
      for (int i=0;i<4;++i)
        #pragma unroll
        for (int j=0;j<4;++j) acc[i][j] += aa[i]*bb[j];
    }
    __syncthreads();
  }
  float* keyv = ws + KEYV_OFF;
  float* valv = ws + VALV_OFF;
  #pragma unroll
  for (int i=0;i<4;++i){
    int n = n0 + ty*4 + i; int b = n / S_; int s = n - b*S_;
    #pragma unroll
    for (int j=0;j<4;++j){
      int c = c0 + tx*4 + j;
      float v = acc[i][j];
      if (c < 128) keyv[((size_t)b*S_+s)*P_ + c]       = v + bk[c];
      else         valv[((size_t)b*S_+s)*P_ + (c-128)] = v + bv[c-128];
    }
  }
}

// ---------------- persistent kernel ------------------------------------------------------
__global__ __launch_bounds__(NTHR, 1) void k_persist(
    const float* __restrict__ embed,
    const float* __restrict__ Wih1, const float* __restrict__ Whh1,
    const float* __restrict__ bih1, const float* __restrict__ bhh1,
    const float* __restrict__ Wih2, const float* __restrict__ Whh2,
    const float* __restrict__ bih2, const float* __restrict__ bhh2,
    const float* __restrict__ Wq, const float* __restrict__ bq,
    const float* __restrict__ bchar, const int* __restrict__ lens,
    float* ws, float* out)
{
  extern __shared__ float smem[];
  const int tid = threadIdx.x;
  const int bid = blockIdx.x;
  int* bar = (int*)(ws + WS_FLOATS);

  float* ctxg = ws + CTX_OFF;
  int*   chrg = (int*)(ws + CHR_OFF);
  float* pv1g = ws + PV1_OFF;
  float* ms1g = ws + MS1_OFF;
  float* es1g = ws + ES1_OFF;

  float* Wl  = smem + W1_BASE;          // [896][16] k-major
  float* W2l = smem + W2_BASE;          // [640][16] k-major
  float* scr = smem + SCR;

  // ---- shared identities ----
  const int sk  = tid & 63;             // staging k within panel (= lane id)
  const int so8 = tid >> 6;             // wave id
  const int lane = tid & 63;

  // ---- phase-1 identity ----
  const int ib  = bid & 1;              // item half (64 items)
  const int ug  = bid >> 1;             // unit group (4 units), 0..127
  const int b0  = ib * 64;
  const int gi8 = b0 + so8*8;
  const int iq  = lane & 15, rq = lane >> 4;
  const int u1  = tid >> 6;
  const int J1  = ug*4 + (u1 & 3);

  // ---- phase-2 identity (bid<128) ----
  const int ig2 = bid & 3;              // item group (32 items)
  const int ug2 = bid >> 2;             // unit group (4 units), 0..31
  const int b02 = ig2 * 32;
  const int gi4 = b02 + so8*4;
  const int iq2 = lane & 7, rq2 = lane >> 3;
  const int u2  = tid >> 5;
  const int J2  = ug2*4 + (u2 & 3);

  // ---- phase-3 identity ----
  const int h3  = bid >> 7;             // s-half (0: blocks 0-127, 1: 128-255)
  const int it3 = bid & 127;            // item
  const float* keyv3 = ws + KEYV_OFF + (size_t)it3*S_*P_;
  const float* valv3 = ws + VALV_OFF + (size_t)it3*S_*P_;
  const int lenb = lens[it3];
  const int s0w = h3*200;
  const int cnt3 = (h3 ? lenb : 200) - s0w;   // h0: 200 always (lens>=200); h1: lenb-200
  const float bqr  = bq[tid >> 2];
  const float bchr = ((tid >> 4) < V_) ? bchar[tid >> 4] : 0.f;
  // phase-3 LDS (persists 3a->3b for blocks 0-127)
  float* qs3   = scr;          // 128
  float* es3   = scr + 128;    // 204
  float* pv0s  = scr + 332;    // 128
  float* ms0s  = scr + 460;    // 2
  float* hs3   = scr + 464;    // 128
  float* redw3 = scr + 592;    // 16
  float* red33 = scr + 608;    // 16*132 = 2112 (ends 2720)
  float* oes3  = scr + 2720;   // 256
  float* pred3 = scr + 2976;   // 32

  // ================= one-time: weight slices into LDS (k-major) ============
  {
    const int r = tid & 15, kb = tid >> 4;
    const int R = (r >> 2)*H_ + ug*4 + (r & 3);
    for (int j = 0; j < 28; ++j){
      int k = kb*28 + j;
      float v = (k < 384) ? Wih1[(size_t)R*384 + k] : Whh1[(size_t)R*H_ + (k-384)];
      Wl[k*16 + r] = v;
    }
  }
  if (bid < 128){
    const int r = tid & 15, kb = tid >> 4;
    const int R = (r >> 2)*D_ + ug2*4 + (r & 3);
    for (int j = 0; j < 20; ++j){
      int k = kb*20 + j;
      float v = (k < 512) ? Wih2[(size_t)R*H_ + k] : Whh2[(size_t)R*D_ + (k-512)];
      W2l[k*16 + r] = v;
    }
  }
  __syncthreads();

  float c1r = 0.f, c2r = 0.f;
  float b1s[4], b2s[4];
  #pragma unroll
  for (int g=0; g<4; ++g){
    b1s[g] = bih1[g*H_ + J1] + bhh1[g*H_ + J1];
    b2s[g] = (bid < 128) ? (bih2[g*D_ + J2] + bhh2[g*D_ + J2]) : 0.f;
  }

  for (int t = 0; t < T_; ++t){
    // ================= Phase 1: LSTM1 (all 256 blocks) ===================
    {
      const float* h1old = ws + H1_OFF + (size_t)(t&1)*B_*H_;
      float*       h1new = ws + H1_OFF + (size_t)((t+1)&1)*B_*H_;
      float* Xs  = scr;                 // [64][64] swizzled
      float* red = scr + 4096;          // [8][16][68]
      int*   schs= (int*)(scr + 13056); // [64]

      if (tid < 64) schs[tid] = ldAi(chrg + b0 + tid);
      __syncthreads();
      int sch8[8];
      #pragma unroll
      for (int j=0;j<8;++j) sch8[j] = schs[so8*8+j];

      float acc[4][4] = {};
      float xr[2][8];
      auto LOADX = [&](int p, float* dst){
        const int kg = p*64 + sk;
        if (kg < 256){
          #pragma unroll
          for (int j=0;j<8;++j) dst[j] = embed[(size_t)sch8[j]*E_ + kg];
        } else if (kg < 384){
          #pragma unroll
          for (int j=0;j<8;++j) dst[j] = ldA(ctxg + (size_t)(gi8+j)*P_ + (kg-256));
        } else {
          #pragma unroll
          for (int j=0;j<8;++j) dst[j] = ldA(h1old + (size_t)(gi8+j)*H_ + (kg-384));
        }
      };
      LOADX(0, xr[0]); LOADX(1, xr[1]);

      for (int p = 0; p < 14; ++p){
        float* xc = xr[p & 1];
        {
          const int s0 = (so8*2 + sk) & 15;
          const int s1 = (so8*2 + 1 + sk) & 15;
          *(float4*)&Xs[sk*64 + s0*4] = make_float4(xc[0],xc[1],xc[2],xc[3]);
          *(float4*)&Xs[sk*64 + s1*4] = make_float4(xc[4],xc[5],xc[6],xc[7]);
        }
        __syncthreads();
        if (p + 2 < 14) LOADX(p + 2, xr[p & 1]);
        // batched LDS reads: issue all 16 ds_read_b128 before the FMA block
        float4 xv[8], wv[8];
        #pragma unroll
        for (int it = 0; it < 8; ++it){
          const int kl = so8*8 + it;
          xv[it] = *(const float4*)&Xs[kl*64 + ((iq + kl) & 15)*4];
          wv[it] = *(const float4*)&Wl[(p*64 + kl)*16 + rq*4];
        }
        #pragma unroll
        for (int it = 0; it < 8; ++it){
          float xa[4] = {xv[it].x, xv[it].y, xv[it].z, xv[it].w};
          float wa[4] = {wv[it].x, wv[it].y, wv[it].z, wv[it].w};
          #pragma unroll
          for (int i=0;i<4;++i)
            #pragma unroll
            for (int j=0;j<4;++j) acc[i][j] += xa[i]*wa[j];
        }
        __syncthreads();
      }
      #pragma unroll
      for (int j=0;j<4;++j)
        *(float4*)&red[so8*1088 + (rq*4+j)*68 + iq*4]
          = make_float4(acc[0][j], acc[1][j], acc[2][j], acc[3][j]);
      __syncthreads();
      if (tid < 256){
        const int item = tid & 63;
        float gate[4];
        #pragma unroll
        for (int g=0; g<4; ++g){
          float s = 0.f;
          #pragma unroll
          for (int w=0; w<8; ++w) s += red[w*1088 + (g*4+(u1&3))*68 + item];
          gate[g] = s + b1s[g];
        }
        float cn = sigm_(gate[1])*c1r + sigm_(gate[0])*tanhf(gate[2]);
        float hn = sigm_(gate[3])*tanhf(cn);
        c1r = cn;
        stA(h1new + (size_t)(b0+item)*H_ + J1, hn);
      }
    }
    gbar(bar);

    // ================= Phase 2: LSTM2 (blocks 0..127) ====================
    if (bid < 128){
      const float* h1n = ws + H1_OFF + (size_t)((t+1)&1)*B_*H_;
      const float* h2o = ws + H2_OFF + (size_t)(t&1)*B_*D_;
      float*       h2n = ws + H2_OFF + (size_t)((t+1)&1)*B_*D_;
      float* Xs2  = scr;                // [64][32] swizzled
      float* red2 = scr + 2048;         // [8][16][36]

      float acc2[4][2] = {};
      float xr2[2][4];
      auto LOADX2 = [&](int p, float* dst){
        const int kg = p*64 + sk;
        if (kg < 512){
          #pragma unroll
          for (int j=0;j<4;++j) dst[j] = ldA(h1n + (size_t)(gi4+j)*H_ + kg);
        } else {
          #pragma unroll
          for (int j=0;j<4;++j) dst[j] = ldA(h2o + (size_t)(gi4+j)*D_ + (kg-512));
        }
      };
      LOADX2(0, xr2[0]); LOADX2(1, xr2[1]);

      for (int p = 0; p < 10; ++p){
        float* xc = xr2[p & 1];
        *(float4*)&Xs2[sk*32 + ((so8 + sk) & 7)*4] = make_float4(xc[0],xc[1],xc[2],xc[3]);
        __syncthreads();
        if (p + 2 < 10) LOADX2(p + 2, xr2[p & 1]);
        float4 xv2[8]; float2 wv2[8];
        #pragma unroll
        for (int it = 0; it < 8; ++it){
          const int kl = so8*8 + it;
          xv2[it] = *(const float4*)&Xs2[kl*32 + ((iq2 + kl) & 7)*4];
          wv2[it] = *(const float2*)&W2l[(p*64 + kl)*16 + rq2*2];
        }
        #pragma unroll
        for (int it = 0; it < 8; ++it){
          float xa[4] = {xv2[it].x, xv2[it].y, xv2[it].z, xv2[it].w};
          #pragma unroll
          for (int i=0;i<4;++i){
            acc2[i][0] += xa[i]*wv2[it].x;
            acc2[i][1] += xa[i]*wv2[it].y;
          }
        }
        __syncthreads();
      }
      #pragma unroll
      for (int j=0;j<2;++j)
        *(float4*)&red2[so8*576 + (rq2*2+j)*36 + iq2*4]
          = make_float4(acc2[0][j], acc2[1][j], acc2[2][j], acc2[3][j]);
      __syncthreads();
      if (tid < 128){
        const int item = tid & 31;
        float gate[4];
        #pragma unroll
        for (int g=0; g<4; ++g){
          float s = 0.f;
          #pragma unroll
          for (int w=0; w<8; ++w) s += red2[w*576 + (g*4+(u2&3))*36 + item];
          gate[g] = s + b2s[g];
        }
        float cn = sigm_(gate[1])*c2r + sigm_(gate[0])*tanhf(gate[2]);
        float hn = sigm_(gate[3])*tanhf(cn);
        c2r = cn;
        stA(h2n + (size_t)(b02+item)*D_ + J2, hn);
      }
    }
    gbar(bar);

    // ================= Phase 3a: attention partials (ALL 256 blocks) ========
    {
      const float* h2new = ws + H2_OFF + (size_t)((t+1)&1)*B_*D_;
      if (tid < 128) hs3[tid] = ldA(h2new + (size_t)it3*D_ + tid);
      __syncthreads();
      {                                  // q = Wq h2 + bq (both halves compute)
        const int r = tid >> 2, kq = tid & 3;
        const float* wr = Wq + (size_t)r*D_ + kq*32;
        float a = 0.f;
        #pragma unroll
        for (int j=0;j<8;++j){
          float4 wvq = *(const float4*)(wr + j*4);
          float4 hv = *(const float4*)&hs3[kq*32 + j*4];
          a += wvq.x*hv.x + wvq.y*hv.y + wvq.z*hv.z + wvq.w*hv.w;
        }
        a += __shfl_down(a, 2, 4);
        a += __shfl_down(a, 1, 4);
        if (kq == 0) qs3[r] = a + bqr;
      }
      __syncthreads();
      const bool act = (tid < cnt3);
      float sv = -INFINITY;
      if (act){                          // scores for this half's window
        const float4* kr = (const float4*)(keyv3 + (size_t)(s0w + tid)*P_);
        float a = 0.f;
        #pragma unroll 8
        for (int d=0; d<32; ++d){
          float4 kv = kr[d];
          float4 qv = *(const float4*)&qs3[d*4];
          a += kv.x*qv.x + kv.y*qv.y + kv.z*qv.z + kv.w*qv.w;
        }
        sv = a * 0.08838834764831845f;
      }
      float mv = sv;
      #pragma unroll
      for (int o=32; o; o>>=1) mv = fmaxf(mv, __shfl_xor(mv, o));
      if ((tid & 63) == 0) redw3[tid >> 6] = mv;
      __syncthreads();
      const float mh = fmaxf(fmaxf(fmaxf(redw3[0],redw3[1]),fmaxf(redw3[2],redw3[3])),
                             fmaxf(fmaxf(redw3[4],redw3[5]),fmaxf(redw3[6],redw3[7])));
      float pv = 0.f;
      if (tid < 200) es3[tid] = 0.f;
      if (act){ pv = expf(sv - mh); es3[tid] = pv; }
      float sm = pv;
      #pragma unroll
      for (int o=32; o; o>>=1) sm += __shfl_xor(sm, o);
      if ((tid & 63) == 0) redw3[8 + (tid >> 6)] = sm;
      __syncthreads();
      const float sumh = ((redw3[8]+redw3[9])+(redw3[10]+redw3[11]))
                       + ((redw3[12]+redw3[13])+(redw3[14]+redw3[15]));
      {                                  // partial PV over this half's rows
        const int p4 = tid & 31, sg = tid >> 5;
        float a0=0,a1=0,a2=0,a3=0;
        const int rend = min(sg*13 + 13, cnt3);
        for (int r = sg*13; r < rend; ++r){
          float e = es3[r];
          float4 v = *(const float4*)(valv3 + (size_t)(s0w + r)*P_ + p4*4);
          a0 += e*v.x; a1 += e*v.y; a2 += e*v.z; a3 += e*v.w;
        }
        *(float4*)&red33[sg*132 + p4*4] = make_float4(a0,a1,a2,a3);
      }
      __syncthreads();
      if (tid < 128){
        float c = 0.f;
        #pragma unroll
        for (int sg=0; sg<16; ++sg) c += red33[sg*132 + tid];
        if (h3 == 0) pv0s[tid] = c;               // keep in LDS (same block does 3b)
        else         stA(pv1g + (size_t)it3*P_ + tid, c);
      }
      if (tid == 0){
        if (h3 == 0){ ms0s[0] = mh; ms0s[1] = sumh; }
        else { stA(ms1g + it3*2, mh); stA(ms1g + it3*2 + 1, sumh); }
      }
      if (h3 == 1 && it3 == 0 && tid < 200) stA(es1g + tid, es3[tid]);
    }
    gbar(bar);

    // ================= Phase 3b: combine + pred + argmax (blocks 0..127) ====
    if (bid < 128){
      const int b = it3;                 // == bid
      const float m1 = ldA(ms1g + b*2);
      const float sum1 = ldA(ms1g + b*2 + 1);
      const float m0 = ms0s[0], sum0 = ms0s[1];
      const float m  = fmaxf(m0, m1);
      const float e0 = expf(m0 - m), e1 = expf(m1 - m);   // m1=-inf -> e1=0
      const float sum = sum0*e0 + sum1*e1;
      if (tid < 128){
        float c = (pv0s[tid]*e0 + ldA(pv1g + (size_t)b*P_ + tid)*e1) / sum;
        stA(ctxg + (size_t)b*P_ + tid, c);
        oes3[tid] = qs3[tid]; oes3[128+tid] = c;
      }
      __syncthreads();
      {                                  // pred + tied-embedding logits
        const int v = tid >> 4, k16 = tid & 15;
        float a = 0.f;
        if (v < V_){
          const float4* er = (const float4*)(embed + (size_t)v*E_ + k16*16);
          #pragma unroll
          for (int j=0;j<4;++j){
            float4 ev = er[j];
            float4 ov = *(const float4*)&oes3[k16*16 + j*4];
            a += ev.x*ov.x + ev.y*ov.y + ev.z*ov.z + ev.w*ov.w;
          }
        }
        a += __shfl_down(a, 8, 16);
        a += __shfl_down(a, 4, 16);
        a += __shfl_down(a, 2, 16);
        a += __shfl_down(a, 1, 16);
        if (v < V_ && k16 == 0){
          float pvv = a + bchr;
          pred3[v] = pvv;
          out[((size_t)b*T_ + t)*V_ + v] = pvv;
        }
      }
      __syncthreads();
      if (tid < 32){                     // argmax (numpy first-index tie-break)
        float val = (tid < V_) ? pred3[tid] : -INFINITY;
        int idx = tid;
        #pragma unroll
        for (int o = 16; o > 0; o >>= 1){
          float ov = __shfl_down(val, o, 32);
          int oi = __shfl_down(idx, o, 32);
          if (ov > val || (ov == val && oi < idx)){ val = ov; idx = oi; }
        }
        if (tid == 0) stAi(chrg + b, idx);
      }
      if (b == 0 && tid < S_){           // attention plot (item 0)
        float val = (tid < 200) ? es3[tid]*e0 : ldA(es1g + tid - 200)*e1;
        out[PRED_N + (size_t)t*S_ + tid] = val / sum;
      }
    }
    gbar(bar);
  }
}

extern "C" void kernel_launch(void* const* d_in, const int* in_sizes, int n_in,
                              void* d_out, int out_size, void* d_ws, size_t ws_size,
                              hipStream_t stream)
{
  (void)in_sizes; (void)n_in; (void)out_size; (void)ws_size;
  const float* enc   = (const float*)d_in[0];
  const int*   lens  = (const int*)d_in[1];
  const float* embed = (const float*)d_in[2];
  const float* Wih1  = (const float*)d_in[3];
  const float* Whh1  = (const float*)d_in[4];
  const float* bih1  = (const float*)d_in[5];
  const float* bhh1  = (const float*)d_in[6];
  const float* Wih2  = (const float*)d_in[7];
  const float* Whh2  = (const float*)d_in[8];
  const float* bih2  = (const float*)d_in[9];
  const float* bhh2  = (const float*)d_in[10];
  const float* Wk    = (const float*)d_in[11];
  const float* bk    = (const float*)d_in[12];
  const float* Wv    = (const float*)d_in[13];
  const float* bv    = (const float*)d_in[14];
  const float* Wq    = (const float*)d_in[15];
  const float* bq    = (const float*)d_in[16];
  const float* bchar = (const float*)d_in[17];
  float* out = (float*)d_out;
  float* ws  = (float*)d_ws;

  // zero recurrent state + partials + barrier region (poison-proof, replay-deterministic)
  hipMemsetAsync((char*)d_ws + (size_t)H1_OFF*sizeof(float), 0,
                 (size_t)(WS_FLOATS - H1_OFF)*sizeof(float) + 2048, stream);
  hipLaunchKernelGGL(k_kv, dim3(800,4), dim3(256), 0, stream, enc, Wk, bk, Wv, bv, ws);

  // 150784 B dynamic LDS -> 1 block/CU, all 256 blocks co-resident (grid barrier safe)
  hipFuncSetAttribute((const void*)k_persist,
                      hipFuncAttributeMaxDynamicSharedMemorySize, LDS_FLOATS*4);
  hipLaunchKernelGGL(k_persist, dim3(NBLK), dim3(NTHR), LDS_FLOATS*4, stream,
                     embed, Wih1, Whh1, bih1, bhh1,
                     Wih2, Whh2, bih2, bhh2,
                     Wq, bq, bchar, lens, ws, out);
}

// Round 8
// 24465.067 us; speedup vs baseline: 1.3009x; 1.3009x over previous
//
#include <hip/hip_runtime.h>
#include <math.h>

// Problem dims
#define B_   128
#define S_   400
#define ENC_ 512
#define E_   256
#define H_   512
#define D_   128
#define P_   128
#define V_   30
#define T_   600

// Workspace layout (float units). Cross-block state TRANSPOSED [feature][batch].
#define KEYV_OFF 0
#define VALV_OFF (KEYV_OFF + B_*S_*P_)
#define H1_OFF   (VALV_OFF + B_*S_*P_)      // 2 x [512][128]
#define H2T_OFF  (H1_OFF + 2*H_*B_)         // 2 x [128][128]
#define H2R_OFF  (H2T_OFF + 2*D_*B_)        // [128][128] row-major copy for P3
#define CTXT_OFF (H2R_OFF + B_*D_)          // [128][128]
#define CHR_OFF  (CTXT_OFF + P_*B_)
#define WS_FLOATS (CHR_OFF + B_)            // barrier ints live at ws[WS_FLOATS..]

#define PRED_N (B_*T_*V_)
#define NBLK 256
#define NTHR 512

// LDS float offsets (k-major weight slices, persistent)
#define W1_BASE 0                           // [896][16]
#define W2_BASE 14336                       // [640][16]
#define SCR     24576                       // per-phase scratch (13120 floats)
#define LDS_FLOATS (SCR + 13120)            // 37696 floats = 150784 B

__device__ __forceinline__ float sigm_(float x){ return 1.0f/(1.0f + expf(-x)); }

// --- agent-scope relaxed atomics (sc1): bypass caches, see coherence point ---
__device__ __forceinline__ float ldA(const float* p){
  return __hip_atomic_load(p, __ATOMIC_RELAXED, __HIP_MEMORY_SCOPE_AGENT);
}
__device__ __forceinline__ void stA(float* p, float v){
  __hip_atomic_store(p, v, __ATOMIC_RELAXED, __HIP_MEMORY_SCOPE_AGENT);
}
__device__ __forceinline__ int ldAi(const int* p){
  return __hip_atomic_load(p, __ATOMIC_RELAXED, __HIP_MEMORY_SCOPE_AGENT);
}
__device__ __forceinline__ void stAi(int* p, int v){
  __hip_atomic_store(p, v, __ATOMIC_RELAXED, __HIP_MEMORY_SCOPE_AGENT);
}
__device__ __forceinline__ void ldA2f(const float* p, float& a, float& b){
  unsigned long long v = __hip_atomic_load((const unsigned long long*)p,
                         __ATOMIC_RELAXED, __HIP_MEMORY_SCOPE_AGENT);
  a = __uint_as_float((unsigned)v);
  b = __uint_as_float((unsigned)(v>>32));
}

// ---- fence-free grid barrier (round-3/4/6/7 proven) ----
__device__ __forceinline__ void gbar(int* bar){
  __syncthreads();
  if (threadIdx.x == 0){
    const int g0 = __hip_atomic_load(bar, __ATOMIC_RELAXED, __HIP_MEMORY_SCOPE_AGENT);
    asm volatile("" ::: "memory");
    int* leaf = bar + 64 + (blockIdx.x & 7)*32;
    int lo = __hip_atomic_fetch_add(leaf, 1, __ATOMIC_RELAXED, __HIP_MEMORY_SCOPE_AGENT);
    bool done = false;
    if (lo == 31){
      int ro = __hip_atomic_fetch_add(bar+32, 1, __ATOMIC_RELAXED, __HIP_MEMORY_SCOPE_AGENT);
      if (ro == 7){
        #pragma unroll
        for (int i=0;i<8;++i)
          __hip_atomic_store(bar+64+i*32, 0, __ATOMIC_RELAXED, __HIP_MEMORY_SCOPE_AGENT);
        __hip_atomic_store(bar+32, 0, __ATOMIC_RELAXED, __HIP_MEMORY_SCOPE_AGENT);
        asm volatile("s_waitcnt vmcnt(0)" ::: "memory");
        __hip_atomic_fetch_add(bar, 1, __ATOMIC_RELAXED, __HIP_MEMORY_SCOPE_AGENT);
        done = true;
      }
    }
    if (!done){
      while (__hip_atomic_load(bar, __ATOMIC_RELAXED, __HIP_MEMORY_SCOPE_AGENT) == g0)
        __builtin_amdgcn_s_sleep(4);
    }
  }
  __syncthreads();
}

// ---------------- precompute keyv/valv fp32 (proven) ------------------------------------
__global__ __launch_bounds__(256) void k_kv(const float* __restrict__ enc,
    const float* __restrict__ Wk, const float* __restrict__ bk,
    const float* __restrict__ Wv, const float* __restrict__ bv,
    float* __restrict__ ws)
{
  __shared__ float As[32][68];
  __shared__ float Bs[32][68];
  const int tid = threadIdx.x;
  const int tx = tid & 15, ty = tid >> 4;
  const int n0 = blockIdx.x * 64;
  const int c0 = blockIdx.y * 64;
  float acc[4][4] = {};
  for (int k0 = 0; k0 < ENC_; k0 += 32){
    #pragma unroll
    for (int i = 0; i < 8; ++i){
      int idx = tid + 256*i;
      int kk = idx & 31, nl = idx >> 5;
      As[kk][nl] = enc[(size_t)(n0+nl)*ENC_ + k0 + kk];
    }
    #pragma unroll
    for (int i = 0; i < 8; ++i){
      int idx = tid + 256*i;
      int kk = idx & 31, cl = idx >> 5;
      int c = c0 + cl; int p = c & 127;
      const float* W = (c < 128) ? Wk : Wv;
      Bs[kk][cl] = W[(size_t)p*ENC_ + k0 + kk];
    }
    __syncthreads();
    #pragma unroll
    for (int kk = 0; kk < 32; ++kk){
      float4 a4 = *(const float4*)&As[kk][ty*4];
      float4 b4 = *(const float4*)&Bs[kk][tx*4];
      float aa[4] = {a4.x, a4.y, a4.z, a4.w};
      float bb[4] = {b4.x, b4.y, b4.z, b4.w};
      #pragma unroll
      for (int i=0;i<4;++i)
        #pragma unroll
        for (int j=0;j<4;++j) acc[i][j] += aa[i]*bb[j];
    }
    __syncthreads();
  }
  float* keyv = ws + KEYV_OFF;
  float* valv = ws + VALV_OFF;
  #pragma unroll
  for (int i=0;i<4;++i){
    int n = n0 + ty*4 + i; int b = n / S_; int s = n - b*S_;
    #pragma unroll
    for (int j=0;j<4;++j){
      int c = c0 + tx*4 + j;
      float v = acc[i][j];
      if (c < 128) keyv[((size_t)b*S_+s)*P_ + c]       = v + bk[c];
      else         valv[((size_t)b*S_+s)*P_ + (c-128)] = v + bv[c-128];
    }
  }
}

// ---------------- persistent kernel ------------------------------------------------------
__global__ __launch_bounds__(NTHR, 1) void k_persist(
    const float* __restrict__ embed,
    const float* __restrict__ Wih1, const float* __restrict__ Whh1,
    const float* __restrict__ bih1, const float* __restrict__ bhh1,
    const float* __restrict__ Wih2, const float* __restrict__ Whh2,
    const float* __restrict__ bih2, const float* __restrict__ bhh2,
    const float* __restrict__ Wq, const float* __restrict__ bq,
    const float* __restrict__ bchar, const int* __restrict__ lens,
    float* ws, float* out)
{
  extern __shared__ float smem[];
  const int tid = threadIdx.x;
  const int bid = blockIdx.x;
  int* bar = (int*)(ws + WS_FLOATS);

  float* ctxT = ws + CTXT_OFF;
  int*   chrg = (int*)(ws + CHR_OFF);
  float* h2R  = ws + H2R_OFF;

  float* Wl  = smem + W1_BASE;          // [896][16] k-major
  float* W2l = smem + W2_BASE;          // [640][16] k-major
  float* scr = smem + SCR;

  const int lane = tid & 63;
  const int so8  = tid >> 6;            // wave id

  // ---- phase-1 identity ----
  const int ib = bid & 1, ug = bid >> 1, b0 = ib*64;
  const int iq = lane & 15, rq = lane >> 4;
  const int u1 = tid >> 6;
  const int J1 = ug*4 + (u1 & 3);
  const int sA  = (tid & 31)*2;         // staging item pair (even)
  const int kbA = tid >> 5;             // 0..15, rows kbA*4+j

  // ---- phase-2 identity (bid<128) ----
  const int ig2 = bid & 3, ug2 = bid >> 2, b02 = ig2*32;
  const int iq2 = lane & 7, rq2 = lane >> 3;
  const int u2 = tid >> 5;
  const int J2 = ug2*4 + (u2 & 3);
  const int sB  = (tid & 15)*2;         // staging item pair (even, 32 items)
  const int kbB = tid >> 4;             // 0..31, rows kbB*2+j

  // ---- phase-3 identity (bid>=128) ----
  const int it3 = bid & 127;
  const float* keyv3 = ws + KEYV_OFF + (size_t)it3*S_*P_;
  const float* valv3 = ws + VALV_OFF + (size_t)it3*S_*P_;
  const int lenb = lens[it3];
  const float bqr  = bq[tid >> 2];
  const float bchr = ((tid >> 4) < V_) ? bchar[tid >> 4] : 0.f;
  // P3 LDS layout inside scr
  float* qs3   = scr;          // 128
  float* es3   = scr + 128;    // 400
  float* hs3   = scr + 528;    // 128
  float* redw3 = scr + 656;    // 16
  float* red33 = scr + 672;    // 16*132 = 2112 (ends 2784)
  float* oes3  = scr + 2784;   // 256
  float* pred3 = scr + 3040;   // 32

  // ================= one-time: weight slices into LDS (k-major) ============
  {
    const int r = tid & 15, kb = tid >> 4;
    const int R = (r >> 2)*H_ + ug*4 + (r & 3);
    for (int j = 0; j < 28; ++j){
      int k = kb*28 + j;
      float v = (k < 384) ? Wih1[(size_t)R*384 + k] : Whh1[(size_t)R*H_ + (k-384)];
      Wl[k*16 + r] = v;
    }
  }
  if (bid < 128){
    const int r = tid & 15, kb = tid >> 4;
    const int R = (r >> 2)*D_ + ug2*4 + (r & 3);
    for (int j = 0; j < 20; ++j){
      int k = kb*20 + j;
      float v = (k < 512) ? Wih2[(size_t)R*H_ + k] : Whh2[(size_t)R*D_ + (k-512)];
      W2l[k*16 + r] = v;
    }
  }
  __syncthreads();

  float c1r = 0.f, c2r = 0.f;
  float b1s[4], b2s[4];
  #pragma unroll
  for (int g=0; g<4; ++g){
    b1s[g] = bih1[g*H_ + J1] + bhh1[g*H_ + J1];
    b2s[g] = (bid < 128) ? (bih2[g*D_ + J2] + bhh2[g*D_ + J2]) : 0.f;
  }

  for (int t = 0; t < T_; ++t){
    // ================= Phase 1: LSTM1 (all 256 blocks) ===================
    {
      const float* h1oT = ws + H1_OFF + (size_t)(t&1)*H_*B_;
      float*       h1nT = ws + H1_OFF + (size_t)((t+1)&1)*H_*B_;
      float* Xs  = scr;                 // [64][64] swizzled rows
      float* red = scr + 4096;          // [8][16][68]
      int*   schs= (int*)(scr + 12800); // [64]

      if (tid < 64) schs[tid] = ldAi(chrg + b0 + tid);
      __syncthreads();
      const int chA = schs[sA], chB = schs[sA+1];

      float xr[4][8];
      auto LOADX = [&](int p, float* dst){
        if (p < 4){                      // embed panels (cached, per-item float4)
          const float4 va = *(const float4*)(embed + (size_t)chA*E_ + p*64 + kbA*4);
          const float4 vb = *(const float4*)(embed + (size_t)chB*E_ + p*64 + kbA*4);
          dst[0]=va.x; dst[1]=vb.x; dst[2]=va.y; dst[3]=vb.y;
          dst[4]=va.z; dst[5]=vb.z; dst[6]=va.w; dst[7]=vb.w;
        } else {                         // state panels: coalesced u64 sc1 loads
          const float* base = (p < 6) ? (ctxT + (size_t)(p*64-256)*B_)
                                      : (h1oT + (size_t)(p*64-384)*B_);
          #pragma unroll
          for (int j=0;j<4;++j)
            ldA2f(base + (size_t)(kbA*4+j)*B_ + b0 + sA, dst[j*2], dst[j*2+1]);
        }
      };
      LOADX(0,xr[0]); LOADX(1,xr[1]); LOADX(2,xr[2]); LOADX(3,xr[3]);

      float acc[4][4] = {};
      for (int p = 0; p < 14; ++p){
        float* xc = xr[p&3];
        #pragma unroll
        for (int j=0;j<4;++j){           // swizzled paired LDS writes
          const int kl = kbA*4 + j;
          float* wp = &Xs[kl*64 + (((sA>>2)+kl)&15)*4 + (sA&3)];
          wp[0] = xc[j*2]; wp[1] = xc[j*2+1];
        }
        __syncthreads();
        if (p + 4 < 14) LOADX(p + 4, xr[p&3]);
        float4 xv[8], wv[8];
        #pragma unroll
        for (int it = 0; it < 8; ++it){  // batched ds_reads
          const int kl = so8*8 + it;
          xv[it] = *(const float4*)&Xs[kl*64 + ((iq + kl)&15)*4];
          wv[it] = *(const float4*)&Wl[(p*64 + kl)*16 + rq*4];
        }
        #pragma unroll
        for (int it = 0; it < 8; ++it){
          float xa[4] = {xv[it].x, xv[it].y, xv[it].z, xv[it].w};
          float wa[4] = {wv[it].x, wv[it].y, wv[it].z, wv[it].w};
          #pragma unroll
          for (int i=0;i<4;++i)
            #pragma unroll
            for (int j=0;j<4;++j) acc[i][j] += xa[i]*wa[j];
        }
        __syncthreads();
      }
      #pragma unroll
      for (int j=0;j<4;++j)
        *(float4*)&red[so8*1088 + (rq*4+j)*68 + iq*4]
          = make_float4(acc[0][j], acc[1][j], acc[2][j], acc[3][j]);
      __syncthreads();
      if (tid < 256){
        const int item = tid & 63;
        float gate[4];
        #pragma unroll
        for (int g=0; g<4; ++g){
          float s = 0.f;
          #pragma unroll
          for (int w=0; w<8; ++w) s += red[w*1088 + (g*4+(u1&3))*68 + item];
          gate[g] = s + b1s[g];
        }
        float cn = sigm_(gate[1])*c1r + sigm_(gate[0])*tanhf(gate[2]);
        float hn = sigm_(gate[3])*tanhf(cn);
        c1r = cn;
        stA(h1nT + (size_t)J1*B_ + b0 + item, hn);   // transposed, coalesced
      }
    }
    gbar(bar);

    // ================= Phase 2: LSTM2 (blocks 0..127) ====================
    if (bid < 128){
      const float* h1nT = ws + H1_OFF + (size_t)((t+1)&1)*H_*B_;
      const float* h2oT = ws + H2T_OFF + (size_t)(t&1)*D_*B_;
      float*       h2nT = ws + H2T_OFF + (size_t)((t+1)&1)*D_*B_;
      float* Xs2  = scr;                // [64][32] swizzled
      float* red2 = scr + 2048;         // [8][16][36]

      float xr2[4][4];
      auto LOADX2 = [&](int p, float* dst){
        const float* base = (p < 8) ? (h1nT + (size_t)(p*64)*B_)
                                    : (h2oT + (size_t)(p*64-512)*B_);
        #pragma unroll
        for (int j=0;j<2;++j)
          ldA2f(base + (size_t)(kbB*2+j)*B_ + b02 + sB, dst[j*2], dst[j*2+1]);
      };
      LOADX2(0,xr2[0]); LOADX2(1,xr2[1]); LOADX2(2,xr2[2]); LOADX2(3,xr2[3]);

      float acc2[4][2] = {};
      for (int p = 0; p < 10; ++p){
        float* xc = xr2[p&3];
        #pragma unroll
        for (int j=0;j<2;++j){
          const int kl = kbB*2 + j;
          float* wp = &Xs2[kl*32 + (((sB>>2)+kl)&7)*4 + (sB&3)];
          wp[0] = xc[j*2]; wp[1] = xc[j*2+1];
        }
        __syncthreads();
        if (p + 4 < 10) LOADX2(p + 4, xr2[p&3]);
        float4 xv2[8]; float2 wv2[8];
        #pragma unroll
        for (int it = 0; it < 8; ++it){
          const int kl = so8*8 + it;
          xv2[it] = *(const float4*)&Xs2[kl*32 + ((iq2 + kl)&7)*4];
          wv2[it] = *(const float2*)&W2l[(p*64 + kl)*16 + rq2*2];
        }
        #pragma unroll
        for (int it = 0; it < 8; ++it){
          float xa[4] = {xv2[it].x, xv2[it].y, xv2[it].z, xv2[it].w};
          #pragma unroll
          for (int i=0;i<4;++i){
            acc2[i][0] += xa[i]*wv2[it].x;
            acc2[i][1] += xa[i]*wv2[it].y;
          }
        }
        __syncthreads();
      }
      #pragma unroll
      for (int j=0;j<2;++j)
        *(float4*)&red2[so8*576 + (rq2*2+j)*36 + iq2*4]
          = make_float4(acc2[0][j], acc2[1][j], acc2[2][j], acc2[3][j]);
      __syncthreads();
      if (tid < 128){
        const int item = tid & 31;
        float gate[4];
        #pragma unroll
        for (int g=0; g<4; ++g){
          float s = 0.f;
          #pragma unroll
          for (int w=0; w<8; ++w) s += red2[w*576 + (g*4+(u2&3))*36 + item];
          gate[g] = s + b2s[g];
        }
        float cn = sigm_(gate[1])*c2r + sigm_(gate[0])*tanhf(gate[2]);
        float hn = sigm_(gate[3])*tanhf(cn);
        c2r = cn;
        stA(h2nT + (size_t)J2*B_ + b02 + item, hn);          // transposed (P2 staging)
        stA(h2R  + (size_t)(b02+item)*D_ + J2, hn);          // row-major (P3 gather)
      }
    }
    gbar(bar);

    // ================= Phase 3: attention + pred + argmax (blocks 128..255) =
    if (bid >= 128){
      if (tid < 128) hs3[tid] = ldA(h2R + (size_t)it3*D_ + tid);  // coalesced
      __syncthreads();
      {                                  // q = Wq h2 + bq, K-split 4 + shfl
        const int r = tid >> 2, kq = tid & 3;
        const float* wr = Wq + (size_t)r*D_ + kq*32;
        float a = 0.f;
        #pragma unroll
        for (int j=0;j<8;++j){
          float4 wvq = *(const float4*)(wr + j*4);
          float4 hv = *(const float4*)&hs3[kq*32 + j*4];
          a += wvq.x*hv.x + wvq.y*hv.y + wvq.z*hv.z + wvq.w*hv.w;
        }
        a += __shfl_down(a, 2, 4);
        a += __shfl_down(a, 1, 4);
        if (kq == 0) qs3[r] = a + bqr;
      }
      __syncthreads();
      float sv = -INFINITY;
      if (tid < lenb){                   // scores only for valid rows
        const float4* kr = (const float4*)(keyv3 + (size_t)tid*P_);
        float a = 0.f;
        #pragma unroll 8
        for (int d=0; d<32; ++d){
          float4 kv = kr[d];
          float4 qv = *(const float4*)&qs3[d*4];
          a += kv.x*qv.x + kv.y*qv.y + kv.z*qv.z + kv.w*qv.w;
        }
        sv = a * 0.08838834764831845f;
      }
      float mv = sv;
      #pragma unroll
      for (int o=32; o; o>>=1) mv = fmaxf(mv, __shfl_xor(mv, o));
      if ((tid & 63) == 0) redw3[tid >> 6] = mv;
      __syncthreads();
      const float m = fmaxf(fmaxf(fmaxf(redw3[0],redw3[1]),fmaxf(redw3[2],redw3[3])),
                            fmaxf(fmaxf(redw3[4],redw3[5]),fmaxf(redw3[6],redw3[7])));
      float pv = 0.f;
      if (tid < lenb){ pv = expf(sv - m); es3[tid] = pv; }
      float sm = pv;
      #pragma unroll
      for (int o=32; o; o>>=1) sm += __shfl_xor(sm, o);
      if ((tid & 63) == 0) redw3[8 + (tid >> 6)] = sm;
      __syncthreads();
      const float sum = ((redw3[8]+redw3[9])+(redw3[10]+redw3[11]))
                      + ((redw3[12]+redw3[13])+(redw3[14]+redw3[15]));
      {                                  // PV: 16-way s-split, len-bounded
        const int p4 = tid & 31, sg = tid >> 5;
        float a0=0,a1=0,a2=0,a3=0;
        const int rend = min(sg*25 + 25, lenb);
        #pragma unroll 4
        for (int r = sg*25; r < rend; ++r){
          float e = es3[r];
          float4 v = *(const float4*)(valv3 + (size_t)r*P_ + p4*4);
          a0 += e*v.x; a1 += e*v.y; a2 += e*v.z; a3 += e*v.w;
        }
        *(float4*)&red33[sg*132 + p4*4] = make_float4(a0,a1,a2,a3);
      }
      __syncthreads();
      if (tid < 128){
        float c = 0.f;
        #pragma unroll
        for (int sg=0; sg<16; ++sg) c += red33[sg*132 + tid];
        c /= sum;
        stA(ctxT + (size_t)tid*B_ + it3, c);
        oes3[tid] = qs3[tid]; oes3[128+tid] = c;
      }
      __syncthreads();
      {                                  // pred + tied-embedding logits
        const int v = tid >> 4, k16 = tid & 15;
        float a = 0.f;
        if (v < V_){
          const float4* er = (const float4*)(embed + (size_t)v*E_ + k16*16);
          #pragma unroll
          for (int j=0;j<4;++j){
            float4 ev = er[j];
            float4 ov = *(const float4*)&oes3[k16*16 + j*4];
            a += ev.x*ov.x + ev.y*ov.y + ev.z*ov.z + ev.w*ov.w;
          }
        }
        a += __shfl_down(a, 8, 16);
        a += __shfl_down(a, 4, 16);
        a += __shfl_down(a, 2, 16);
        a += __shfl_down(a, 1, 16);
        if (v < V_ && k16 == 0){
          float pvv = a + bchr;
          pred3[v] = pvv;
          out[((size_t)it3*T_ + t)*V_ + v] = pvv;
        }
      }
      __syncthreads();
      if (tid < 32){                     // argmax (numpy first-index tie-break)
        float val = (tid < V_) ? pred3[tid] : -INFINITY;
        int idx = tid;
        #pragma unroll
        for (int o = 16; o > 0; o >>= 1){
          float ov = __shfl_down(val, o, 32);
          int oi = __shfl_down(idx, o, 32);
          if (ov > val || (ov == val && oi < idx)){ val = ov; idx = oi; }
        }
        if (tid == 0) stAi(chrg + it3, idx);
      }
      if (it3 == 0 && tid < S_)          // plot: masked rows exactly 0
        out[PRED_N + (size_t)t*S_ + tid] = (tid < lenb) ? es3[tid]/sum : 0.f;
    }
    gbar(bar);
  }
}

extern "C" void kernel_launch(void* const* d_in, const int* in_sizes, int n_in,
                              void* d_out, int out_size, void* d_ws, size_t ws_size,
                              hipStream_t stream)
{
  (void)in_sizes; (void)n_in; (void)out_size; (void)ws_size;
  const float* enc   = (const float*)d_in[0];
  const int*   lens  = (const int*)d_in[1];
  const float* embed = (const float*)d_in[2];
  const float* Wih1  = (const float*)d_in[3];
  const float* Whh1  = (const float*)d_in[4];
  const float* bih1  = (const float*)d_in[5];
  const float* bhh1  = (const float*)d_in[6];
  const float* Wih2  = (const float*)d_in[7];
  const float* Whh2  = (const float*)d_in[8];
  const float* bih2  = (const float*)d_in[9];
  const float* bhh2  = (const float*)d_in[10];
  const float* Wk    = (const float*)d_in[11];
  const float* bk    = (const float*)d_in[12];
  const float* Wv    = (const float*)d_in[13];
  const float* bv    = (const float*)d_in[14];
  const float* Wq    = (const float*)d_in[15];
  const float* bq    = (const float*)d_in[16];
  const float* bchar = (const float*)d_in[17];
  float* out = (float*)d_out;
  float* ws  = (float*)d_ws;

  // zero recurrent state + barrier region (poison-proof, replay-deterministic)
  hipMemsetAsync((char*)d_ws + (size_t)H1_OFF*sizeof(float), 0,
                 (size_t)(WS_FLOATS - H1_OFF)*sizeof(float) + 2048, stream);
  hipLaunchKernelGGL(k_kv, dim3(800,4), dim3(256), 0, stream, enc, Wk, bk, Wv, bv, ws);

  // 150784 B dynamic LDS -> 1 block/CU, all 256 blocks co-resident (grid barrier safe)
  hipFuncSetAttribute((const void*)k_persist,
                      hipFuncAttributeMaxDynamicSharedMemorySize, LDS_FLOATS*4);
  hipLaunchKernelGGL(k_persist, dim3(NBLK), dim3(NTHR), LDS_FLOATS*4, stream,
                     embed, Wih1, Whh1, bih1, bhh1,
                     Wih2, Whh2, bih2, bhh2,
                     Wq, bq, bchar, lens, ws, out);
}